// Round 4
// baseline (231.480 us; speedup 1.0000x reference)
//
#include <hip/hip_runtime.h>
#include <hip/hip_bf16.h>

#define CELL 128
#define STEPS 20

// packed-bf16 (two per uint) -> float
__device__ __forceinline__ float b2f_lo(unsigned u) { return __uint_as_float(u << 16); }
__device__ __forceinline__ float b2f_hi(unsigned u) { return __uint_as_float(u & 0xffff0000u); }
// float -> bf16 bits, round-to-nearest-even
__device__ __forceinline__ unsigned f2b_bits(float f) {
    unsigned u = __float_as_uint(f);
    return (u + 0x7fffu + ((u >> 16) & 1u)) >> 16;
}

__device__ __forceinline__ float fast_sigmoid(float x) { return 1.0f / (1.0f + __expf(-x)); }
__device__ __forceinline__ float fast_tanh(float x) {
    return 2.0f / (1.0f + __expf(-2.0f * x)) - 1.0f;   // fp32, ample precision
}

// One workgroup runs the whole 20-step recurrence on one CU.
// Inputs fp32 (reference dtype); OUTPUT fp32 (reference output dtype).
// Thread g (0..511) owns gate row g of W_ih/W_hh, packed to bf16 in 128 VGPRs.
// x and h live in LDS as fp32 (same-address broadcast reads, conflict-free).
extern "C" __global__ void __launch_bounds__(512, 2)
nas_policy_kernel(const int* __restrict__ net,
                  const float* __restrict__ emb_start,   // [1][128]
                  const float* __restrict__ emb_keys,    // [4][6][128]
                  const float* __restrict__ fc_W,        // [4][6][128]
                  const float* __restrict__ fc_b,        // [4][6]
                  const float* __restrict__ W_ih,        // [512][128]
                  const float* __restrict__ W_hh,        // [512][128]
                  const float* __restrict__ b_ih,        // [512]
                  const float* __restrict__ b_hh,        // [512]
                  float* __restrict__ out)               // [20][1][6] fp32
{
    const int g = threadIdx.x;

    __shared__ __align__(16) float xh[2 * CELL];   // [0..127]=x, [128..255]=h
    __shared__ float gates[4 * CELL];
    __shared__ float logits[8];
    __shared__ int   s_net[STEPS];

    // ---- preload weight row g, packing fp32 -> bf16 pairs (64+64 VGPRs) ----
    unsigned wih[64], whh[64];
    {
        const float4* p = (const float4*)W_ih + (size_t)g * 32;
#pragma unroll
        for (int q = 0; q < 32; ++q) {
            float4 a = p[q];
            wih[2 * q]     = f2b_bits(a.x) | (f2b_bits(a.y) << 16);
            wih[2 * q + 1] = f2b_bits(a.z) | (f2b_bits(a.w) << 16);
        }
    }
    {
        const float4* p = (const float4*)W_hh + (size_t)g * 32;
#pragma unroll
        for (int q = 0; q < 32; ++q) {
            float4 a = p[q];
            whh[2 * q]     = f2b_bits(a.x) | (f2b_bits(a.y) << 16);
            whh[2 * q + 1] = f2b_bits(a.z) | (f2b_bits(a.w) << 16);
        }
    }
    const float bias = b_ih[g] + b_hh[g];   // fp32, unquantized

    // ---- init: x = emb_start, h = 0, c = 0 ----
    if (g < CELL) { xh[g] = emb_start[g]; xh[CELL + g] = 0.0f; }
    if (g < STEPS) s_net[g] = net[g];
    float c = 0.0f;

    const int wv   = g >> 6;   // wave id 0..7
    const int lane = g & 63;

    for (int t = 0; t < STEPS; ++t) {
        __syncthreads();   // xh (and init staging) ready; prev logits consumed

        // ---- gates[g] = bias + W_ih[g].x + W_hh[g].h ----
        const float4* x4 = (const float4*)xh;
        float a0 = 0.f, a1 = 0.f, a2 = 0.f, a3 = 0.f;
#pragma unroll
        for (int q = 0; q < 32; ++q) {
            float4 u = x4[q];                 // x[4q..4q+3]
            unsigned w0 = wih[2 * q], w1 = wih[2 * q + 1];
            a0 = fmaf(b2f_lo(w0), u.x, a0); a1 = fmaf(b2f_hi(w0), u.y, a1);
            a2 = fmaf(b2f_lo(w1), u.z, a2); a3 = fmaf(b2f_hi(w1), u.w, a3);
        }
#pragma unroll
        for (int q = 0; q < 32; ++q) {
            float4 u = x4[32 + q];            // h[4q..4q+3]
            unsigned w0 = whh[2 * q], w1 = whh[2 * q + 1];
            a0 = fmaf(b2f_lo(w0), u.x, a0); a1 = fmaf(b2f_hi(w0), u.y, a1);
            a2 = fmaf(b2f_lo(w1), u.z, a2); a3 = fmaf(b2f_hi(w1), u.w, a3);
        }
        gates[g] = bias + (a0 + a1) + (a2 + a3);

        __syncthreads();   // gates ready

        // ---- LSTM elementwise (threads 0..127) + stage next-step x ----
        if (g < CELL) {
            float ig = fast_sigmoid(gates[g]);
            float fg = fast_sigmoid(gates[CELL + g]);
            float gg = fast_tanh   (gates[2 * CELL + g]);
            float og = fast_sigmoid(gates[3 * CELL + g]);
            c = fg * c + ig * gg;
            float h = og * fast_tanh(c);
            xh[CELL + g] = h;
            xh[g] = emb_keys[(((t & 3) * 6) + s_net[t]) * CELL + g];  // next x
        }

        __syncthreads();   // h ready

        // ---- head logits: wave r (r<6) computes h . fc_W[t%4][r] (fp32) ----
        if (wv < 6) {
            const float* Wr = fc_W + (((t & 3) * 6) + wv) * CELL;
            float p = xh[CELL + lane]      * Wr[lane]
                    + xh[CELL + 64 + lane] * Wr[64 + lane];
#pragma unroll
            for (int off = 32; off >= 1; off >>= 1) p += __shfl_down(p, off);
            if (lane == 0) logits[wv] = p + fc_b[(t & 3) * 6 + wv];
        }

        __syncthreads();   // logits ready

        // ---- softmax over 6 + fp32 output (threads 0..5, redundant) ----
        if (g < 6) {
            float l0 = logits[0], l1 = logits[1], l2 = logits[2];
            float l3 = logits[3], l4 = logits[4], l5 = logits[5];
            float m = fmaxf(fmaxf(fmaxf(l0, l1), fmaxf(l2, l3)), fmaxf(l4, l5));
            float e0 = __expf(l0 - m), e1 = __expf(l1 - m), e2 = __expf(l2 - m);
            float e3 = __expf(l3 - m), e4 = __expf(l4 - m), e5 = __expf(l5 - m);
            float s = ((e0 + e1) + (e2 + e3)) + (e4 + e5);
            float mine = (g == 0) ? e0 : (g == 1) ? e1 : (g == 2) ? e2
                       : (g == 3) ? e3 : (g == 4) ? e4 : e5;
            out[t * 6 + g] = mine / s;    // fp32 store — reference output dtype
        }
    }
}

extern "C" void kernel_launch(void* const* d_in, const int* in_sizes, int n_in,
                              void* d_out, int out_size, void* d_ws, size_t ws_size,
                              hipStream_t stream) {
    (void)in_sizes; (void)n_in; (void)out_size; (void)d_ws; (void)ws_size;
    const int*   net       = (const int*)d_in[0];
    // d_in[1] = reward, unused in forward
    const float* emb_start = (const float*)d_in[2];
    const float* emb_keys  = (const float*)d_in[3];
    const float* fc_W      = (const float*)d_in[4];
    const float* fc_b      = (const float*)d_in[5];
    const float* W_ih      = (const float*)d_in[6];
    const float* W_hh      = (const float*)d_in[7];
    const float* b_ih      = (const float*)d_in[8];
    const float* b_hh      = (const float*)d_in[9];
    float*       out       = (float*)d_out;

    hipLaunchKernelGGL(nas_policy_kernel, dim3(1), dim3(512), 0, stream,
                       net, emb_start, emb_keys, fc_W, fc_b,
                       W_ih, W_hh, b_ih, b_hh, out);
}

// Round 5
// 210.187 us; speedup vs baseline: 1.1013x; 1.1013x over previous
//
#include <hip/hip_runtime.h>
#include <hip/hip_fp16.h>

#define CELL 128
#define STEPS 20

__device__ __forceinline__ float fast_sigmoid(float x) { return 1.0f / (1.0f + __expf(-x)); }
__device__ __forceinline__ float fast_tanh(float x) {
    return 2.0f / (1.0f + __expf(-2.0f * x)) - 1.0f;   // fp32, ample precision
}

// One 1024-thread workgroup runs the whole 20-step recurrence on one CU.
// Inputs fp32, output fp32 (verified R4). Gate row g's 256-wide concat row
// [W_ih[g] | W_hh[g]] is split across lane pair (2g, 2g+1): even lane holds
// the W_ih half (dots with x), odd lane the W_hh half (dots with h), each as
// 64 __half2 regs (f16). Partner partials combine via __shfl_xor(p,1).
// 64 weight regs/thread keeps us far from the 128-VGPR cap => no scratch
// spill (R4's 162 KB WRITE_SIZE = 81 spilled dwords/thread was the killer).
extern "C" __global__ void __launch_bounds__(1024, 4)
nas_policy_kernel(const int* __restrict__ net,
                  const float* __restrict__ emb_start,   // [1][128]
                  const float* __restrict__ emb_keys,    // [4][6][128]
                  const float* __restrict__ fc_W,        // [4][6][128]
                  const float* __restrict__ fc_b,        // [4][6]
                  const float* __restrict__ W_ih,        // [512][128]
                  const float* __restrict__ W_hh,        // [512][128]
                  const float* __restrict__ b_ih,        // [512]
                  const float* __restrict__ b_hh,        // [512]
                  float* __restrict__ out)               // [20][1][6] fp32
{
    const int t0   = threadIdx.x;    // 0..1023
    const int g    = t0 >> 1;        // gate row 0..511
    const int half = t0 & 1;         // 0: W_ih half (x), 1: W_hh half (h)

    __shared__ __align__(16) float xh[2 * CELL];   // [0..127]=x, [128..255]=h
    __shared__ float gates[4 * CELL];
    __shared__ float logits[8];
    __shared__ float s_embk[24 * CELL];            // emb_keys staged fp32
    __shared__ float s_fcW[24 * CELL];             // fc_W staged fp32
    __shared__ float s_fcb[24];
    __shared__ int   s_net[STEPS];

    // ---- pack this thread's 128 weights into 64 half2 regs (f16) ----
    __half2 wreg[64];
    {
        const float4* s4 = (const float4*)((half ? W_hh : W_ih) + (size_t)g * CELL);
#pragma unroll
        for (int q = 0; q < 32; ++q) {
            float4 a = s4[q];
            wreg[2 * q]     = __floats2half2_rn(a.x, a.y);
            wreg[2 * q + 1] = __floats2half2_rn(a.z, a.w);
        }
    }
    const float bias = b_ih[g] + b_hh[g];   // fp32, used by even lane only

    // ---- stage small tensors to LDS; init x, h, c ----
    for (int i = t0; i < 24 * CELL; i += 1024) { s_embk[i] = emb_keys[i]; s_fcW[i] = fc_W[i]; }
    if (t0 < 24)    s_fcb[t0] = fc_b[t0];
    if (t0 < STEPS) s_net[t0] = net[t0];
    if (t0 < CELL)  { xh[t0] = emb_start[t0]; xh[CELL + t0] = 0.0f; }
    float c = 0.0f;

    const int wv    = t0 >> 6;       // wave 0..15
    const int lane  = t0 & 63;
    const int xbase = half * 32;     // even lanes read x (float4 0..31), odd read h (32..63)

    for (int t = 0; t < STEPS; ++t) {
        __syncthreads();   // A: xh (and init staging) ready; prev logits consumed

        // ---- half-row dot: p = w[0..127] . xh[half*128 .. +128] ----
        const float4* x4 = (const float4*)xh;
        float a0 = 0.f, a1 = 0.f, a2 = 0.f, a3 = 0.f;
#pragma unroll
        for (int q = 0; q < 32; ++q) {
            float4 u = x4[xbase + q];
            __half2 w0 = wreg[2 * q], w1 = wreg[2 * q + 1];
            a0 = fmaf(__low2float(w0),  u.x, a0);   // v_fma_mix candidates
            a1 = fmaf(__high2float(w0), u.y, a1);
            a2 = fmaf(__low2float(w1),  u.z, a2);
            a3 = fmaf(__high2float(w1), u.w, a3);
        }
        float p = (a0 + a1) + (a2 + a3);
        p += __shfl_xor(p, 1);                      // combine x-half + h-half
        if (half == 0) gates[g] = bias + p;

        __syncthreads();   // B: gates ready

        // ---- LSTM elementwise (threads 0..127) + stage next-step x ----
        if (t0 < CELL) {
            float ig = fast_sigmoid(gates[t0]);
            float fg = fast_sigmoid(gates[CELL + t0]);
            float gg = fast_tanh   (gates[2 * CELL + t0]);
            float og = fast_sigmoid(gates[3 * CELL + t0]);
            c = fg * c + ig * gg;
            float h = og * fast_tanh(c);
            xh[CELL + t0] = h;
            xh[t0] = s_embk[(((t & 3) * 6) + s_net[t]) * CELL + t0];  // next x
        }

        __syncthreads();   // C: h ready

        // ---- head logits: wave r (r<6) computes h . fc_W[t%4][r] ----
        if (wv < 6) {
            const float* Wr = s_fcW + (((t & 3) * 6) + wv) * CELL;
            float p2 = xh[CELL + lane]      * Wr[lane]
                     + xh[CELL + 64 + lane] * Wr[64 + lane];
#pragma unroll
            for (int off = 32; off >= 1; off >>= 1) p2 += __shfl_down(p2, off);
            if (lane == 0) logits[wv] = p2 + s_fcb[(t & 3) * 6 + wv];
        }

        __syncthreads();   // D: logits ready

        // ---- softmax over 6 + fp32 output (threads 0..5, redundant) ----
        if (t0 < 6) {
            float l0 = logits[0], l1 = logits[1], l2 = logits[2];
            float l3 = logits[3], l4 = logits[4], l5 = logits[5];
            float m = fmaxf(fmaxf(fmaxf(l0, l1), fmaxf(l2, l3)), fmaxf(l4, l5));
            float e0 = __expf(l0 - m), e1 = __expf(l1 - m), e2 = __expf(l2 - m);
            float e3 = __expf(l3 - m), e4 = __expf(l4 - m), e5 = __expf(l5 - m);
            float s = ((e0 + e1) + (e2 + e3)) + (e4 + e5);
            float mine = (t0 == 0) ? e0 : (t0 == 1) ? e1 : (t0 == 2) ? e2
                       : (t0 == 3) ? e3 : (t0 == 4) ? e4 : e5;
            out[t * 6 + t0] = mine / s;
        }
    }
}

extern "C" void kernel_launch(void* const* d_in, const int* in_sizes, int n_in,
                              void* d_out, int out_size, void* d_ws, size_t ws_size,
                              hipStream_t stream) {
    (void)in_sizes; (void)n_in; (void)out_size; (void)d_ws; (void)ws_size;
    const int*   net       = (const int*)d_in[0];
    // d_in[1] = reward, unused in forward
    const float* emb_start = (const float*)d_in[2];
    const float* emb_keys  = (const float*)d_in[3];
    const float* fc_W      = (const float*)d_in[4];
    const float* fc_b      = (const float*)d_in[5];
    const float* W_ih      = (const float*)d_in[6];
    const float* W_hh      = (const float*)d_in[7];
    const float* b_ih      = (const float*)d_in[8];
    const float* b_hh      = (const float*)d_in[9];
    float*       out       = (float*)d_out;

    hipLaunchKernelGGL(nas_policy_kernel, dim3(1), dim3(1024), 0, stream,
                       net, emb_start, emb_keys, fc_W, fc_b,
                       W_ih, W_hh, b_ih, b_hh, out);
}